// Round 1
// baseline (188.391 us; speedup 1.0000x reference)
//
#include <hip/hip_runtime.h>

#define B_DIM   2048
#define IN_DIM  4096
#define OUT_DIM 4096
#define FAN     64

// Design:
//  - block = 256 threads, each thread owns ONE output neuron o.
//  - grid  = (32 b-segments of 64 rows) x (16 o-blocks of 256 neurons) = 512 blocks
//            -> 2 blocks/CU (64 KB LDS each, 128 KB <= 160 KB).
//  - per b-tile (8 rows): rows staged into LDS as bf16, packed 8-rows-per-cell:
//        cell c (16 B, uint4) = column c of rows b0..b0+7, word w = rows (2w,2w+1).
//    One ds_read_b128 gathers a column for 8 batch rows -> 8 MACs.
//  - idx is pre-converted to swizzled LDS BYTE addresses held in registers;
//    weights held in registers; zero address math in the inner loop.
//  - staging-write swizzle p(c) = c ^ ((c>>3)&7) makes ds_write_b32 pattern
//    2-way (free); read side stays uniform (p is a bijection, folded into addrs).

__device__ __forceinline__ unsigned bf16_rne(float f) {
    unsigned u = __float_as_uint(f);
    return (u + 0x7fffu + ((u >> 16) & 1u)) >> 16;   // round-to-nearest-even bf16
}

__device__ __forceinline__ unsigned swz(int c) {
    return (unsigned)(c ^ ((c >> 3) & 7));
}

__global__ __launch_bounds__(256, 2) void condensed_kernel(
    const float* __restrict__ input,
    const float* __restrict__ weight,
    const float* __restrict__ bias,
    const int*   __restrict__ mask,
    float*       __restrict__ out)
{
    __shared__ __align__(16) unsigned lds[IN_DIM * 4];   // 64 KB

    const int tid  = threadIdx.x;
    const int o    = blockIdx.y * 256 + tid;
    const int bseg = blockIdx.x * 64;

    // ---- load idx (as swizzled LDS byte offsets) + weights into registers ----
    unsigned addrs[FAN];
    float    wv[FAN];
    {
        const int4*   mv = reinterpret_cast<const int4*>(mask)     + o * (FAN / 4);
        const float4* wp = reinterpret_cast<const float4*>(weight) + o * (FAN / 4);
        #pragma unroll
        for (int j = 0; j < FAN / 4; ++j) {
            int4   m4 = mv[j];
            float4 w4 = wp[j];
            addrs[4*j+0] = swz(m4.x) << 4;
            addrs[4*j+1] = swz(m4.y) << 4;
            addrs[4*j+2] = swz(m4.z) << 4;
            addrs[4*j+3] = swz(m4.w) << 4;
            wv[4*j+0] = w4.x;
            wv[4*j+1] = w4.y;
            wv[4*j+2] = w4.z;
            wv[4*j+3] = w4.w;
        }
    }
    const float bv = bias[o];

    const int wsel = tid & 3;            // which word (row-pair) this thread stages

    for (int bt = 0; bt < 8; ++bt) {
        const int b0 = bseg + bt * 8;

        __syncthreads();                 // protect previous tile's readers

        // ---- stage 8 rows (fp32 -> bf16 packed) into LDS ----
        // item = it*256+tid: wsel = item&3 (== tid&3), cell group = item>>2.
        // Thread loads float4 from rows (b0+2*wsel, b0+2*wsel+1), packs 4 cells.
        {
            const float* rowA = input + (size_t)(b0 + 2 * wsel) * IN_DIM;
            const float* rowB = rowA + IN_DIM;
            #pragma unroll
            for (int it = 0; it < 16; ++it) {
                const int cb = ((it * 256 + tid) >> 2) * 4;   // [0,4096), mult of 4
                const float4 a = *reinterpret_cast<const float4*>(rowA + cb);
                const float4 b = *reinterpret_cast<const float4*>(rowB + cb);
                lds[(swz(cb + 0) << 2) + wsel] = bf16_rne(a.x) | (bf16_rne(b.x) << 16);
                lds[(swz(cb + 1) << 2) + wsel] = bf16_rne(a.y) | (bf16_rne(b.y) << 16);
                lds[(swz(cb + 2) << 2) + wsel] = bf16_rne(a.z) | (bf16_rne(b.z) << 16);
                lds[(swz(cb + 3) << 2) + wsel] = bf16_rne(a.w) | (bf16_rne(b.w) << 16);
            }
        }

        __syncthreads();

        // ---- gather + accumulate: 64 x ds_read_b128, 8 rows each ----
        float acc[8];
        #pragma unroll
        for (int r = 0; r < 8; ++r) acc[r] = 0.0f;

        #pragma unroll
        for (int j = 0; j < FAN; ++j) {
            const uint4 g = *reinterpret_cast<const uint4*>(
                reinterpret_cast<const char*>(lds) + addrs[j]);
            const float wj = wv[j];
            acc[0] = fmaf(__uint_as_float(g.x << 16),          wj, acc[0]);
            acc[1] = fmaf(__uint_as_float(g.x & 0xffff0000u),  wj, acc[1]);
            acc[2] = fmaf(__uint_as_float(g.y << 16),          wj, acc[2]);
            acc[3] = fmaf(__uint_as_float(g.y & 0xffff0000u),  wj, acc[3]);
            acc[4] = fmaf(__uint_as_float(g.z << 16),          wj, acc[4]);
            acc[5] = fmaf(__uint_as_float(g.z & 0xffff0000u),  wj, acc[5]);
            acc[6] = fmaf(__uint_as_float(g.w << 16),          wj, acc[6]);
            acc[7] = fmaf(__uint_as_float(g.w & 0xffff0000u),  wj, acc[7]);
        }

        // ---- write 8 outputs (coalesced across threads) ----
        float* op = out + (size_t)b0 * OUT_DIM + o;
        #pragma unroll
        for (int r = 0; r < 8; ++r) {
            op[(size_t)r * OUT_DIM] = acc[r] + bv;
        }
    }
}

extern "C" void kernel_launch(void* const* d_in, const int* in_sizes, int n_in,
                              void* d_out, int out_size, void* d_ws, size_t ws_size,
                              hipStream_t stream) {
    const float* input  = (const float*)d_in[0];
    const float* weight = (const float*)d_in[1];
    const float* bias   = (const float*)d_in[2];
    const int*   mask   = (const int*)d_in[3];
    float*       out    = (float*)d_out;

    dim3 grid(32, 16);   // 32 b-segments x 16 o-blocks = 512 blocks = 2/CU
    condensed_kernel<<<grid, 256, 0, stream>>>(input, weight, bias, mask, out);
}